// Round 8
// baseline (102.898 us; speedup 1.0000x reference)
//
#include <hip/hip_runtime.h>
#include <hip/hip_bf16.h>
#include <stdint.h>

// Problem constants (from reference)
#define Bq 32
#define Sq 512
#define Hq 1024
#define Tq 100
#define Fq 512
#define Lq 5
#define EPSq 1e-5f

typedef float fx4 __attribute__((ext_vector_type(4)));
typedef __bf16 bfx8 __attribute__((ext_vector_type(8)));
typedef unsigned short u16x8 __attribute__((ext_vector_type(8)));

static __device__ __forceinline__ unsigned short f2bf(float f) {
  unsigned int u = __builtin_bit_cast(unsigned int, f);
  return (unsigned short)((u + 0x7fffu + ((u >> 16) & 1u)) >> 16);  // RNE (finite inputs)
}
static __device__ __forceinline__ float bf2f(unsigned short s) {
  return __builtin_bit_cast(float, ((unsigned int)s) << 16);
}
// async global->LDS, 16B per lane; LDS dest must be wave-linear (base + lane*16)
static __device__ __forceinline__ void gl_lds16(const void* g, void* l) {
  __builtin_amdgcn_global_load_lds(
      (const __attribute__((address_space(1))) unsigned int*)(uintptr_t)g,
      (__attribute__((address_space(3))) unsigned int*)(uintptr_t)l,
      16, 0, 0);
}

// ---------------------------------------------------------------- fused: seq f32->bf16 convert  +  W1 transpose->bf16
__global__ void k_prep(const float* __restrict__ seq, unsigned short* __restrict__ seqbf,
                       const float* __restrict__ w1, unsigned short* __restrict__ w1t) {
  int blk = blockIdx.x;
  int tid = threadIdx.x;
  if (blk < 8192) {
    int i = blk * 256 + tid;   // 8 elems per thread, grid exact
    const float4* p = (const float4*)seq + (size_t)i * 2;
    float4 a = p[0], b = p[1];
    u16x8 o;
    o[0] = f2bf(a.x); o[1] = f2bf(a.y); o[2] = f2bf(a.z); o[3] = f2bf(a.w);
    o[4] = f2bf(b.x); o[5] = f2bf(b.y); o[6] = f2bf(b.z); o[7] = f2bf(b.w);
    *((u16x8*)seqbf + i) = o;
  } else {
    __shared__ float t[32][33];
    int bb = blk - 8192;
    int l = bb >> 10; int rem = bb & 1023; int tr = rem >> 5; int tc = rem & 31;
    const float* src = w1 + (size_t)l * Hq * Hq;
    unsigned short* dst = w1t + (size_t)l * Hq * Hq;
    int tx = tid & 31, ty = tid >> 5;  // 32 x 8
#pragma unroll
    for (int p = 0; p < 4; p++)
      t[ty + 8 * p][tx] = src[(size_t)(tr * 32 + ty + 8 * p) * Hq + tc * 32 + tx];
    __syncthreads();
#pragma unroll
    for (int p = 0; p < 4; p++)
      dst[(size_t)(tc * 32 + ty + 8 * p) * Hq + tr * 32 + tx] = f2bf(t[tx][ty + 8 * p]);
  }
}

// ---------------------------------------------------------------- GEMM1: H1 = seq @ W1[lang] + b1, bf16 out
// 256x256 block tile, 512 thr = 8 waves (2 wr x 4 wc), wave tile 128x64. Grid = 256 = 1 blk/CU.
// K-loop: 32 half-steps (BK=32); 4-slot LDS ring (128KB); depth-3 staging, counted vmcnt(8)
// at hs top (R6/R7-proven WAR pattern). NEW (m201 phase schedule): each half-step split into
// 2 phases of 16 MFMA — {ds_reads; barrier; lgkmcnt(0); sched_barrier; setprio(1) MFMA x16
// setprio(0); barrier}. Double barrier bounds skew so peer waves' MFMA clusters overlap this
// wave's LDS-read wait instead of serializing (m196/m201: the fine interleave is the lever).
__global__ __launch_bounds__(512, 2) void k_gemm1(const unsigned short* __restrict__ seqbf,
                                                  const unsigned short* __restrict__ w1t,
                                                  const float* __restrict__ b1,
                                                  const int* __restrict__ lid,
                                                  unsigned short* __restrict__ h1bf) {
  __shared__ short sA[4][256 * 32];
  __shared__ short sB[4][256 * 32];
  int bid = blockIdx.x;
  int g = bid & 63; int tn = bid >> 6;   // XCD = bid%8 = g%8: all 4 tn of a (b,tm) co-XCD
  int b = g >> 1; int tm = g & 1;
  int lang = lid[b];
  const unsigned short* Ab = seqbf + (size_t)b * Sq * Hq + (size_t)tm * 256 * Hq;
  const unsigned short* Bb = w1t + (size_t)lang * Hq * Hq + (size_t)tn * 256 * Hq;

  int tid = threadIdx.x;
  int lane = tid & 63; int wid = tid >> 6;
  int wr = wid >> 2, wc = wid & 3;       // 2 x 4 wave grid; wave tile 128 x 64
  int fr = lane & 15;                    // A row / B col within 16
  int q = lane >> 4;                     // 16B chunk within 64B row
  int key = ((fr >> 1) & 7) << 4;        // frag-read swizzle key (per-lane const)

  // staging: 16KB half-tile = 1024 x 16B chunks; thread covers chunks tid, tid+512
  const unsigned short* gA[2]; const unsigned short* gB[2]; int dstOff[2];
#pragma unroll
  for (int j = 0; j < 2; j++) {
    int p = (tid + j * 512) * 16;        // linear LDS byte offset
    int l = p ^ ((p >> 3) & 0x70);       // inverse-swizzled logical position
    int R = l >> 6, qa = (l >> 4) & 3;
    gA[j] = Ab + (size_t)R * Hq + qa * 8;
    gB[j] = Bb + (size_t)R * Hq + qa * 8;
    dstOff[j] = p;
  }

  // fragment read byte offsets (stored)
  int aOff[8], bOff[4];
#pragma unroll
  for (int m = 0; m < 8; m++)
    aOff[m] = ((wr * 128 + m * 16 + fr) * 64 + q * 16) ^ key;
#pragma unroll
  for (int n = 0; n < 4; n++)
    bOff[n] = ((wc * 64 + n * 16 + fr) * 64 + q * 16) ^ key;

  fx4 acc[8][4];
#pragma unroll
  for (int m = 0; m < 8; m++)
#pragma unroll
    for (int n = 0; n < 4; n++) acc[m][n] = (fx4){0.f, 0.f, 0.f, 0.f};

  // prologue: stage half-tiles 0,1,2 into slots 0,1,2 (12 loads in flight)
#pragma unroll
  for (int s = 0; s < 3; s++) {
#pragma unroll
    for (int j = 0; j < 2; j++) {
      gl_lds16(gA[j] + s * 32, (char*)sA[s] + dstOff[j]);
      gl_lds16(gB[j] + s * 32, (char*)sB[s] + dstOff[j]);
    }
  }

  for (int hs = 0; hs < 32; hs++) {
    int cur = hs & 3;
    // hs top: slot cur DMA complete (oldest 4 loads drained); hs+1/hs+2 stay in flight.
    // lgkmcnt(0): every wave's ds_reads retired before ANY wave passes -> WAR-safe vs the
    // stage issued below (which overwrites slot (hs+3)&3, read last at hs-1).
    if (hs < 30)
      asm volatile("s_waitcnt vmcnt(8) lgkmcnt(0)\n\ts_barrier" ::: "memory");
    else if (hs == 30)
      asm volatile("s_waitcnt vmcnt(4) lgkmcnt(0)\n\ts_barrier" ::: "memory");
    else
      asm volatile("s_waitcnt vmcnt(0) lgkmcnt(0)\n\ts_barrier" ::: "memory");
    if (hs <= 28) {                      // stage hs+3 -> slot (hs+3)&3
      int slot = (hs + 3) & 3;
      int ko = (hs + 3) * 32;
#pragma unroll
      for (int j = 0; j < 2; j++) {
        gl_lds16(gA[j] + ko, (char*)sA[slot] + dstOff[j]);
        gl_lds16(gB[j] + ko, (char*)sB[slot] + dstOff[j]);
      }
    }
    const char* cA = (const char*)sA[cur];
    const char* cB = (const char*)sB[cur];

    // ---- phase 0: B frags + A rows 0..63 -> 16 MFMA
    bfx8 bf[4], af[4];
#pragma unroll
    for (int n = 0; n < 4; n++) bf[n] = *(const bfx8*)(cB + bOff[n]);
#pragma unroll
    for (int m = 0; m < 4; m++) af[m] = *(const bfx8*)(cA + aOff[m]);
    __builtin_amdgcn_s_barrier();
    asm volatile("s_waitcnt lgkmcnt(0)" ::: "memory");
    __builtin_amdgcn_sched_barrier(0);   // pin MFMAs behind the wait (rule #18)
    __builtin_amdgcn_s_setprio(1);
#pragma unroll
    for (int m = 0; m < 4; m++)
#pragma unroll
      for (int n = 0; n < 4; n++)
        acc[m][n] = __builtin_amdgcn_mfma_f32_16x16x32_bf16(af[m], bf[n], acc[m][n], 0, 0, 0);
    __builtin_amdgcn_s_setprio(0);
    __builtin_amdgcn_s_barrier();

    // ---- phase 1: A rows 64..127 -> 16 MFMA
    bfx8 af2[4];
#pragma unroll
    for (int m = 0; m < 4; m++) af2[m] = *(const bfx8*)(cA + aOff[4 + m]);
    __builtin_amdgcn_s_barrier();
    asm volatile("s_waitcnt lgkmcnt(0)" ::: "memory");
    __builtin_amdgcn_sched_barrier(0);
    __builtin_amdgcn_s_setprio(1);
#pragma unroll
    for (int m = 0; m < 4; m++)
#pragma unroll
      for (int n = 0; n < 4; n++)
        acc[4 + m][n] = __builtin_amdgcn_mfma_f32_16x16x32_bf16(af2[m], bf[n], acc[4 + m][n], 0, 0, 0);
    __builtin_amdgcn_s_setprio(0);
    // no trailing barrier: next hs-top waitcnt+barrier closes the phase
  }

  // epilogue: + b1, convert, store bf16. C/D: row=(lane>>4)*4+r, col=lane&15 (R2-verified)
  unsigned short* Cb = h1bf + (size_t)b * Sq * Hq;
  float bv[4];
#pragma unroll
  for (int n = 0; n < 4; n++)
    bv[n] = b1[lang * Hq + tn * 256 + wc * 64 + n * 16 + fr];
  int r0 = q * 4;
#pragma unroll
  for (int m = 0; m < 8; m++) {
#pragma unroll
    for (int n = 0; n < 4; n++) {
      int col = tn * 256 + wc * 64 + n * 16 + fr;
#pragma unroll
      for (int r = 0; r < 4; r++) {
        int row = tm * 256 + wr * 128 + m * 16 + r0 + r;
        Cb[(size_t)row * Hq + col] = f2bf(acc[m][n][r] + bv[n]);
      }
    }
  }
}

// ---------------------------------------------------------------- LN + relu + masked pool partials
__global__ __launch_bounds__(256) void k_ln_pool(const unsigned short* __restrict__ h1bf,
                                                 const float* __restrict__ g1,
                                                 const float* __restrict__ be1,
                                                 const float* __restrict__ mask,
                                                 const int* __restrict__ lid,
                                                 float* __restrict__ partial) {
  __shared__ float sacc[4][1024];
  int blk = blockIdx.x; int b = blk >> 3; int ch = blk & 7;
  int tid = threadIdx.x; int lane = tid & 63; int w = tid >> 6;
  int lang = lid[b];
  int e0 = lane * 8;
  int e1 = 512 + lane * 8;

  const float4* gp = (const float4*)(g1 + (size_t)lang * Hq);
  const float4* bp = (const float4*)(be1 + (size_t)lang * Hq);
  float4 ga0 = gp[lane * 2], ga1 = gp[lane * 2 + 1];
  float4 gb0 = gp[128 + lane * 2], gb1 = gp[129 + lane * 2];
  float4 ba0 = bp[lane * 2], ba1 = bp[lane * 2 + 1];
  float4 bb0 = bp[128 + lane * 2], bb1 = bp[129 + lane * 2];
  float gA[8] = {ga0.x, ga0.y, ga0.z, ga0.w, ga1.x, ga1.y, ga1.z, ga1.w};
  float gB[8] = {gb0.x, gb0.y, gb0.z, gb0.w, gb1.x, gb1.y, gb1.z, gb1.w};
  float bA[8] = {ba0.x, ba0.y, ba0.z, ba0.w, ba1.x, ba1.y, ba1.z, ba1.w};
  float bB[8] = {bb0.x, bb0.y, bb0.z, bb0.w, bb1.x, bb1.y, bb1.z, bb1.w};

  float acc0[8] = {0, 0, 0, 0, 0, 0, 0, 0}, acc1[8] = {0, 0, 0, 0, 0, 0, 0, 0};

  for (int i = 0; i < 16; i++) {
    int s = ch * 64 + w * 16 + i;
    const unsigned short* rowp = h1bf + ((size_t)b * Sq + s) * Hq;
    u16x8 va = *(const u16x8*)(rowp + e0);
    u16x8 vb = *(const u16x8*)(rowp + e1);
    float xa[8], xb[8];
    float sum = 0.f, sq = 0.f;
#pragma unroll
    for (int j = 0; j < 8; j++) {
      xa[j] = bf2f(va[j]); sum += xa[j]; sq += xa[j] * xa[j];
      xb[j] = bf2f(vb[j]); sum += xb[j]; sq += xb[j] * xb[j];
    }
#pragma unroll
    for (int off = 1; off < 64; off <<= 1) {
      sum += __shfl_xor(sum, off, 64);
      sq += __shfl_xor(sq, off, 64);
    }
    float mu = sum * (1.f / Hq);
    float var = sq * (1.f / Hq) - mu * mu;
    float rstd = rsqrtf(var + EPSq);
    float mw = mask[b * Sq + s];
#pragma unroll
    for (int j = 0; j < 8; j++) {
      float y0 = fmaxf((xa[j] - mu) * rstd * gA[j] + bA[j], 0.f);
      float y1 = fmaxf((xb[j] - mu) * rstd * gB[j] + bB[j], 0.f);
      acc0[j] += mw * y0;
      acc1[j] += mw * y1;
    }
  }
#pragma unroll
  for (int j = 0; j < 8; j++) {
    sacc[w][e0 + j] = acc0[j];
    sacc[w][e1 + j] = acc1[j];
  }
  __syncthreads();
  int e = tid * 4;
#pragma unroll
  for (int j = 0; j < 4; j++)
    partial[(size_t)blk * Hq + e + j] =
        sacc[0][e + j] + sacc[1][e + j] + sacc[2][e + j] + sacc[3][e + j];
}

// ---------------------------------------------------------------- reduce partials, / masksum
__global__ void k_reduce_pool(const float* __restrict__ partial, const float* __restrict__ mask,
                              float* __restrict__ pooled) {
  __shared__ float wsum[4];
  int b = blockIdx.x; int tid = threadIdx.x;  // 256
  float mv = mask[b * Sq + tid] + mask[b * Sq + 256 + tid];
#pragma unroll
  for (int off = 1; off < 64; off <<= 1) mv += __shfl_xor(mv, off, 64);
  if ((tid & 63) == 0) wsum[tid >> 6] = mv;
  __syncthreads();
  float inv = 1.0f / (wsum[0] + wsum[1] + wsum[2] + wsum[3]);
  int e = tid * 4;
#pragma unroll
  for (int j = 0; j < 4; j++) {
    float s = 0.f;
#pragma unroll
    for (int c = 0; c < 8; c++) s += partial[((size_t)b * 8 + c) * Hq + e + j];
    pooled[b * Hq + e + j] = s * inv;
  }
}

// ---------------------------------------------------------------- pooled @ W2[lang] split-K partials
__global__ __launch_bounds__(256) void k_gemm2p(const float* __restrict__ pooled,
                                                const float* __restrict__ w2,
                                                const int* __restrict__ lid,
                                                float* __restrict__ g2part) {
  __shared__ float pl[256];
  int blk = blockIdx.x;
  int b = blk >> 3; int ch = (blk >> 2) & 1; int ks = blk & 3;
  int tid = threadIdx.x;
  int lang = lid[b];
  pl[tid] = pooled[b * Hq + ks * 256 + tid];
  __syncthreads();
  int col = ch * 512 + tid * 2;
  const float* W = w2 + (size_t)lang * Hq * Hq + (size_t)ks * 256 * Hq + col;
  float a0 = 0.f, a1 = 0.f;
  for (int e0 = 0; e0 < 256; e0 += 8) {
    float2 w[8];
#pragma unroll
    for (int j = 0; j < 8; j++) w[j] = *(const float2*)(W + (size_t)(e0 + j) * Hq);
#pragma unroll
    for (int j = 0; j < 8; j++) { float c = pl[e0 + j]; a0 += c * w[j].x; a1 += c * w[j].y; }
  }
  float2* dst = (float2*)(g2part + ((size_t)(b * 4 + ks) * Hq) + col);
  *dst = make_float2(a0, a1);
}

// ---------------------------------------------------------------- sum k-slices + b2 -> pooledf
__global__ __launch_bounds__(256) void k_gemm2red(const float* __restrict__ g2part,
                                                  const float* __restrict__ b2,
                                                  const int* __restrict__ lid,
                                                  float* __restrict__ pooledf) {
  int b = blockIdx.x; int tid = threadIdx.x;
  int lang = lid[b];
  int col = tid * 4;
  float4 acc = *(const float4*)(b2 + (size_t)lang * Hq + col);
#pragma unroll
  for (int ks = 0; ks < 4; ks++) {
    float4 p = *(const float4*)(g2part + ((size_t)(b * 4 + ks) * Hq) + col);
    acc.x += p.x; acc.y += p.y; acc.z += p.z; acc.w += p.w;
  }
  *(float4*)(pooledf + (size_t)b * Hq + col) = acc;
}

// ---------------------------------------------------------------- final matmul split-K partials
__global__ __launch_bounds__(256) void k_fpart(const float* __restrict__ pooledf,
                                               const float* __restrict__ lda,
                                               const float* __restrict__ wf,
                                               float* __restrict__ fpart) {
  __shared__ float sc[128];
  int blk = blockIdx.x;
  int b = blk / 9, ks = blk % 9;
  int tid = threadIdx.x;
  int klen = (ks < 8) ? 128 : 100;
  int kbase = (ks < 8) ? ks * 128 : Hq;   // row offset into wf
  if (tid < klen) sc[tid] = (ks < 8) ? pooledf[b * Hq + kbase + tid] : lda[b * Tq + tid];
  __syncthreads();
  const float* W = wf + (size_t)kbase * Fq + tid * 2;
  float a0 = 0.f, a1 = 0.f;
  int k0 = 0;
  for (; k0 + 8 <= klen; k0 += 8) {
    float2 w[8];
#pragma unroll
    for (int j = 0; j < 8; j++) w[j] = *(const float2*)(W + (size_t)(k0 + j) * Fq);
#pragma unroll
    for (int j = 0; j < 8; j++) { float c = sc[k0 + j]; a0 += c * w[j].x; a1 += c * w[j].y; }
  }
  for (; k0 < klen; k0++) {
    float2 w = *(const float2*)(W + (size_t)k0 * Fq);
    float c = sc[k0];
    a0 += c * w.x; a1 += c * w.y;
  }
  float2* dst = (float2*)(fpart + (size_t)blk * Fq + tid * 2);
  *dst = make_float2(a0, a1);
}

// ---------------------------------------------------------------- reduce 9 slices + bf, LN, relu -> f32 out
__global__ __launch_bounds__(512) void k_final2(const float* __restrict__ fpart,
                                                const float* __restrict__ bff,
                                                const float* __restrict__ gf,
                                                const float* __restrict__ betaf,
                                                float* __restrict__ out) {
  __shared__ float rsum[8], rsq[8];
  int b = blockIdx.x; int tid = threadIdx.x;  // 512
  float acc = bff[tid];
#pragma unroll
  for (int ks = 0; ks < 9; ks++) acc += fpart[((size_t)b * 9 + ks) * Fq + tid];
  float s = acc, q = acc * acc;
#pragma unroll
  for (int off = 1; off < 64; off <<= 1) {
    s += __shfl_xor(s, off, 64);
    q += __shfl_xor(q, off, 64);
  }
  int w = tid >> 6, lane = tid & 63;
  if (lane == 0) { rsum[w] = s; rsq[w] = q; }
  __syncthreads();
  float S = 0.f, Q = 0.f;
#pragma unroll
  for (int i = 0; i < 8; i++) { S += rsum[i]; Q += rsq[i]; }
  float mu = S * (1.f / Fq);
  float var = Q * (1.f / Fq) - mu * mu;
  float y = (acc - mu) * rsqrtf(var + EPSq) * gf[tid] + betaf[tid];
  y = fmaxf(y, 0.f);
  out[b * Fq + tid] = y;   // f32 output
}

// ----------------------------------------------------------------
extern "C" void kernel_launch(void* const* d_in, const int* in_sizes, int n_in,
                              void* d_out, int out_size, void* d_ws, size_t ws_size,
                              hipStream_t stream) {
  const float* seq = (const float*)d_in[0];
  const float* mask = (const float*)d_in[1];
  const int* lid = (const int*)d_in[2];
  const float* lda = (const float*)d_in[3];
  const float* W1 = (const float*)d_in[4];
  const float* b1 = (const float*)d_in[5];
  const float* g1 = (const float*)d_in[6];
  const float* be1 = (const float*)d_in[7];
  const float* W2 = (const float*)d_in[8];
  const float* b2 = (const float*)d_in[9];
  const float* Wf = (const float*)d_in[10];
  const float* bff = (const float*)d_in[11];
  const float* gf = (const float*)d_in[12];
  const float* betaf = (const float*)d_in[13];
  float* out = (float*)d_out;

  // workspace layout (~80 MB)
  char* ws = (char*)d_ws;
  unsigned short* seqbf = (unsigned short*)(ws);                  // 33,554,432 B
  unsigned short* w1t = (unsigned short*)(ws + 33554432);         // 10,485,760 B
  unsigned short* h1bf = (unsigned short*)(ws + 44040192);        // 33,554,432 B
  float* partial = (float*)(ws + 77594624);                       //  1,048,576 B
  float* pooled = (float*)(ws + 78643200);                        //    131,072 B
  float* pooledf = (float*)(ws + 78774272);                       //    131,072 B
  float* g2part = (float*)(ws + 78905344);                        //    524,288 B
  float* fpart = (float*)(ws + 79429632);                         //    589,824 B

  k_prep<<<13312, 256, 0, stream>>>(seq, seqbf, W1, w1t);
  k_gemm1<<<256, 512, 0, stream>>>(seqbf, w1t, b1, lid, h1bf);
  k_ln_pool<<<256, 256, 0, stream>>>(h1bf, g1, be1, mask, lid, partial);
  k_reduce_pool<<<32, 256, 0, stream>>>(partial, mask, pooled);
  k_gemm2p<<<256, 256, 0, stream>>>(pooled, W2, lid, g2part);
  k_gemm2red<<<32, 256, 0, stream>>>(g2part, b2, lid, pooledf);
  k_fpart<<<288, 256, 0, stream>>>(pooledf, lda, Wf, fpart);
  k_final2<<<32, 512, 0, stream>>>(fpart, bff, gf, betaf, out);
}

// Round 9
// 91.232 us; speedup vs baseline: 1.1279x; 1.1279x over previous
//
#include <hip/hip_runtime.h>
#include <hip/hip_bf16.h>
#include <stdint.h>

// Problem constants (from reference)
#define Bq 32
#define Sq 512
#define Hq 1024
#define Tq 100
#define Fq 512
#define Lq 5
#define EPSq 1e-5f

typedef float fx4 __attribute__((ext_vector_type(4)));
typedef __bf16 bfx8 __attribute__((ext_vector_type(8)));
typedef unsigned short u16x8 __attribute__((ext_vector_type(8)));

static __device__ __forceinline__ unsigned short f2bf(float f) {
  unsigned int u = __builtin_bit_cast(unsigned int, f);
  return (unsigned short)((u + 0x7fffu + ((u >> 16) & 1u)) >> 16);  // RNE (finite inputs)
}
static __device__ __forceinline__ float bf2f(unsigned short s) {
  return __builtin_bit_cast(float, ((unsigned int)s) << 16);
}
static __device__ __forceinline__ u16x8 cvt8(float4 x0, float4 x1) {
  u16x8 r;
  r[0] = f2bf(x0.x); r[1] = f2bf(x0.y); r[2] = f2bf(x0.z); r[3] = f2bf(x0.w);
  r[4] = f2bf(x1.x); r[5] = f2bf(x1.y); r[6] = f2bf(x1.z); r[7] = f2bf(x1.w);
  return r;
}
// async global->LDS, 16B per lane; LDS dest must be wave-linear (base + lane*16)
static __device__ __forceinline__ void gl_lds16(const void* g, void* l) {
  __builtin_amdgcn_global_load_lds(
      (const __attribute__((address_space(1))) unsigned int*)(uintptr_t)g,
      (__attribute__((address_space(3))) unsigned int*)(uintptr_t)l,
      16, 0, 0);
}

// ---------------------------------------------------------------- W1 [L][H][H] f32 -> W1T [L][e][h] bf16
__global__ void k_prep(const float* __restrict__ w1, unsigned short* __restrict__ w1t) {
  __shared__ float t[32][33];
  int blk = blockIdx.x;
  int l = blk >> 10; int rem = blk & 1023; int tr = rem >> 5; int tc = rem & 31;
  const float* src = w1 + (size_t)l * Hq * Hq;
  unsigned short* dst = w1t + (size_t)l * Hq * Hq;
  int tid = threadIdx.x;
  int tx = tid & 31, ty = tid >> 5;  // 32 x 8
#pragma unroll
  for (int p = 0; p < 4; p++)
    t[ty + 8 * p][tx] = src[(size_t)(tr * 32 + ty + 8 * p) * Hq + tc * 32 + tx];
  __syncthreads();
#pragma unroll
  for (int p = 0; p < 4; p++)
    dst[(size_t)(tc * 32 + ty + 8 * p) * Hq + tr * 32 + tx] = f2bf(t[tx][ty + 8 * p]);
}

// ---------------------------------------------------------------- GEMM1: H1 = seq @ W1[lang] + b1, bf16 out
// 256x256 tile, 8 waves (2wr x 4wc), wave tile 128x64, 32 half-steps BK=32, 4-slot LDS ring.
// R9: A read DIRECTLY from seq f32, T14 reg-staged (cvt tile hs+2 at step2; load hs+3 at step3)
// with swizzled ds_write_b128 (write-side + read-side swizzle, rule-#21 reg-staging form).
// B unchanged: gl_lds16, linear dest, pre-inverse-swizzled source.
// vmcnt ledger per iter j: [top-wait][step2 cvt+write A(j+2) — auto-wait drains A(j+2) and
// everything older, incl. B(j+1)][step3 load A(j+3)->rA][step4 B(j+3) DMA][reads+MFMA].
// Inductively B(j) is drained at j-1's step2 => top wait = vmcnt(4) (allows B(j+1),B(j+2) in
// flight) + lgkmcnt(0) (ds_reads retired -> WAR vs DMA; ds_writes retired -> visibility).
// hs=31 uses vmcnt(0) (B(31) staged last at hs=28, no cvt after hs=29 to force-drain it).
// Slot WAR: A write at j -> slot (j+2)&3, last read j-2, retired by (j-1)-top. B DMA at j ->
// slot (j+3)&3, last read j-1, retired by j-top. Both safe.
__global__ __launch_bounds__(512, 2) void k_gemm1(const float* __restrict__ seq,
                                                  const unsigned short* __restrict__ w1t,
                                                  const float* __restrict__ b1,
                                                  const int* __restrict__ lid,
                                                  unsigned short* __restrict__ h1bf) {
  __shared__ short sA[4][256 * 32];
  __shared__ short sB[4][256 * 32];
  int bid = blockIdx.x;
  int g = bid & 63; int tn = bid >> 6;   // XCD = bid%8 = g%8: all 4 tn of a (b,tm) co-XCD
  int b = g >> 1; int tm = g & 1;
  int lang = lid[b];
  const float* Abf = seq + (size_t)b * Sq * Hq + (size_t)tm * 256 * Hq;     // f32 A panel
  const unsigned short* Bb = w1t + (size_t)lang * Hq * Hq + (size_t)tn * 256 * Hq;

  int tid = threadIdx.x;
  int lane = tid & 63; int wid = tid >> 6;
  int wr = wid >> 2, wc = wid & 3;       // 2 x 4 wave grid; wave tile 128 x 64
  int fr = lane & 15;                    // A row / B col within 16
  int q = lane >> 4;                     // 16B chunk within 64B row
  int key = ((fr >> 1) & 7) << 4;        // frag-read swizzle key (per-lane const)

  // A reg-staging: logical chunk c = tid, tid+512 -> row R=c>>2, qa=c&3.
  // ds_write byte = (R*64+qa*16) ^ swz ; global f32 src = Abf + R*Hq + qa*8 (+tile*32).
  const float* gAf0; const float* gAf1; int aW0, aW1;
  {
    int c0 = tid;        int R0 = c0 >> 2, q0 = c0 & 3; int y0 = R0 * 64 + q0 * 16;
    int c1 = tid + 512;  int R1 = c1 >> 2, q1 = c1 & 3; int y1 = R1 * 64 + q1 * 16;
    aW0 = y0 ^ ((y0 >> 3) & 0x70);
    aW1 = y1 ^ ((y1 >> 3) & 0x70);
    gAf0 = Abf + (size_t)R0 * Hq + q0 * 8;
    gAf1 = Abf + (size_t)R1 * Hq + q1 * 8;
  }
  // B gl_lds staging: linear dest chunk p, pre-inverse-swizzled global source
  const unsigned short* gB[2]; int dstOff[2];
#pragma unroll
  for (int j = 0; j < 2; j++) {
    int p = (tid + j * 512) * 16;
    int l = p ^ ((p >> 3) & 0x70);
    int R = l >> 6, qa = (l >> 4) & 3;
    gB[j] = Bb + (size_t)R * Hq + qa * 8;
    dstOff[j] = p;
  }

  // fragment read byte offsets (stored)
  int aOff[8], bOff[4];
#pragma unroll
  for (int m = 0; m < 8; m++)
    aOff[m] = ((wr * 128 + m * 16 + fr) * 64 + q * 16) ^ key;
#pragma unroll
  for (int n = 0; n < 4; n++)
    bOff[n] = ((wc * 64 + n * 16 + fr) * 64 + q * 16) ^ key;

  fx4 acc[8][4];
#pragma unroll
  for (int m = 0; m < 8; m++)
#pragma unroll
    for (int n = 0; n < 4; n++) acc[m][n] = (fx4){0.f, 0.f, 0.f, 0.f};

  float4 ra0a, ra0b, ra1a, ra1b;  // rA: f32 for the tile staged at step2 (named, static — rule #20)

  // prologue: A tiles 0,1 load+cvt+write; A tile 2 load into rA; B DMA tiles 0,1,2.
  // (A2-load older than B0 in queue -> j=0's vmcnt(4) drains A2+B0.)
#pragma unroll
  for (int t = 0; t < 2; t++) {
    ra0a = *(const float4*)(gAf0 + t * 32); ra0b = *(const float4*)(gAf0 + t * 32 + 4);
    ra1a = *(const float4*)(gAf1 + t * 32); ra1b = *(const float4*)(gAf1 + t * 32 + 4);
    *(u16x8*)((char*)sA[t] + aW0) = cvt8(ra0a, ra0b);
    *(u16x8*)((char*)sA[t] + aW1) = cvt8(ra1a, ra1b);
  }
  ra0a = *(const float4*)(gAf0 + 64); ra0b = *(const float4*)(gAf0 + 68);
  ra1a = *(const float4*)(gAf1 + 64); ra1b = *(const float4*)(gAf1 + 68);
#pragma unroll
  for (int s = 0; s < 3; s++) {
    gl_lds16(gB[0] + s * 32, (char*)sB[s] + dstOff[0]);
    gl_lds16(gB[1] + s * 32, (char*)sB[s] + dstOff[1]);
  }

  for (int hs = 0; hs < 32; hs++) {
    int cur = hs & 3;
    if (hs < 31)
      asm volatile("s_waitcnt vmcnt(4) lgkmcnt(0)\n\ts_barrier" ::: "memory");
    else
      asm volatile("s_waitcnt vmcnt(0) lgkmcnt(0)\n\ts_barrier" ::: "memory");
    // step2: cvt + ds_write tile hs+2 -> slot (hs+2)&3 (read at hs-2; WAR-safe)
    if (hs <= 29) {
      int sa = (hs + 2) & 3;
      *(u16x8*)((char*)sA[sa] + aW0) = cvt8(ra0a, ra0b);
      *(u16x8*)((char*)sA[sa] + aW1) = cvt8(ra1a, ra1b);
    }
    // step3: load A f32 tile hs+3 -> rA
    if (hs <= 28) {
      int ko = (hs + 3) * 32;
      ra0a = *(const float4*)(gAf0 + ko); ra0b = *(const float4*)(gAf0 + ko + 4);
      ra1a = *(const float4*)(gAf1 + ko); ra1b = *(const float4*)(gAf1 + ko + 4);
    }
    // step4: B DMA tile hs+3 -> slot (hs+3)&3 (read at hs-1; WAR-safe via this top's barrier)
    if (hs <= 28) {
      int ko = (hs + 3) * 32;
      gl_lds16(gB[0] + ko, (char*)sB[(hs + 3) & 3] + dstOff[0]);
      gl_lds16(gB[1] + ko, (char*)sB[(hs + 3) & 3] + dstOff[1]);
    }
    // compute on slot cur
    const char* cA = (const char*)sA[cur];
    const char* cB = (const char*)sB[cur];
    bfx8 bf[4], af[8];
#pragma unroll
    for (int n = 0; n < 4; n++) bf[n] = *(const bfx8*)(cB + bOff[n]);
#pragma unroll
    for (int m = 0; m < 8; m++) af[m] = *(const bfx8*)(cA + aOff[m]);
    __builtin_amdgcn_s_setprio(1);
#pragma unroll
    for (int m = 0; m < 8; m++)
#pragma unroll
      for (int n = 0; n < 4; n++)
        acc[m][n] = __builtin_amdgcn_mfma_f32_16x16x32_bf16(af[m], bf[n], acc[m][n], 0, 0, 0);
    __builtin_amdgcn_s_setprio(0);
  }

  // epilogue: + b1, convert, store bf16. C/D: row=(lane>>4)*4+r, col=lane&15 (R2-verified)
  unsigned short* Cb = h1bf + (size_t)b * Sq * Hq;
  float bv[4];
#pragma unroll
  for (int n = 0; n < 4; n++)
    bv[n] = b1[lang * Hq + tn * 256 + wc * 64 + n * 16 + fr];
  int r0 = q * 4;
#pragma unroll
  for (int m = 0; m < 8; m++) {
#pragma unroll
    for (int n = 0; n < 4; n++) {
      int col = tn * 256 + wc * 64 + n * 16 + fr;
#pragma unroll
      for (int r = 0; r < 4; r++) {
        int row = tm * 256 + wr * 128 + m * 16 + r0 + r;
        Cb[(size_t)row * Hq + col] = f2bf(acc[m][n][r] + bv[n]);
      }
    }
  }
}

// ---------------------------------------------------------------- LN + relu + masked pool partials
__global__ __launch_bounds__(256) void k_ln_pool(const unsigned short* __restrict__ h1bf,
                                                 const float* __restrict__ g1,
                                                 const float* __restrict__ be1,
                                                 const float* __restrict__ mask,
                                                 const int* __restrict__ lid,
                                                 float* __restrict__ partial) {
  __shared__ float sacc[4][1024];
  int blk = blockIdx.x; int b = blk >> 3; int ch = blk & 7;
  int tid = threadIdx.x; int lane = tid & 63; int w = tid >> 6;
  int lang = lid[b];
  int e0 = lane * 8;
  int e1 = 512 + lane * 8;

  const float4* gp = (const float4*)(g1 + (size_t)lang * Hq);
  const float4* bp = (const float4*)(be1 + (size_t)lang * Hq);
  float4 ga0 = gp[lane * 2], ga1 = gp[lane * 2 + 1];
  float4 gb0 = gp[128 + lane * 2], gb1 = gp[129 + lane * 2];
  float4 ba0 = bp[lane * 2], ba1 = bp[lane * 2 + 1];
  float4 bb0 = bp[128 + lane * 2], bb1 = bp[129 + lane * 2];
  float gA[8] = {ga0.x, ga0.y, ga0.z, ga0.w, ga1.x, ga1.y, ga1.z, ga1.w};
  float gB[8] = {gb0.x, gb0.y, gb0.z, gb0.w, gb1.x, gb1.y, gb1.z, gb1.w};
  float bA[8] = {ba0.x, ba0.y, ba0.z, ba0.w, ba1.x, ba1.y, ba1.z, ba1.w};
  float bB[8] = {bb0.x, bb0.y, bb0.z, bb0.w, bb1.x, bb1.y, bb1.z, bb1.w};

  float acc0[8] = {0, 0, 0, 0, 0, 0, 0, 0}, acc1[8] = {0, 0, 0, 0, 0, 0, 0, 0};

  for (int i = 0; i < 16; i++) {
    int s = ch * 64 + w * 16 + i;
    const unsigned short* rowp = h1bf + ((size_t)b * Sq + s) * Hq;
    u16x8 va = *(const u16x8*)(rowp + e0);
    u16x8 vb = *(const u16x8*)(rowp + e1);
    float xa[8], xb[8];
    float sum = 0.f, sq = 0.f;
#pragma unroll
    for (int j = 0; j < 8; j++) {
      xa[j] = bf2f(va[j]); sum += xa[j]; sq += xa[j] * xa[j];
      xb[j] = bf2f(vb[j]); sum += xb[j]; sq += xb[j] * xb[j];
    }
#pragma unroll
    for (int off = 1; off < 64; off <<= 1) {
      sum += __shfl_xor(sum, off, 64);
      sq += __shfl_xor(sq, off, 64);
    }
    float mu = sum * (1.f / Hq);
    float var = sq * (1.f / Hq) - mu * mu;
    float rstd = rsqrtf(var + EPSq);
    float mw = mask[b * Sq + s];
#pragma unroll
    for (int j = 0; j < 8; j++) {
      float y0 = fmaxf((xa[j] - mu) * rstd * gA[j] + bA[j], 0.f);
      float y1 = fmaxf((xb[j] - mu) * rstd * gB[j] + bB[j], 0.f);
      acc0[j] += mw * y0;
      acc1[j] += mw * y1;
    }
  }
#pragma unroll
  for (int j = 0; j < 8; j++) {
    sacc[w][e0 + j] = acc0[j];
    sacc[w][e1 + j] = acc1[j];
  }
  __syncthreads();
  int e = tid * 4;
#pragma unroll
  for (int j = 0; j < 4; j++)
    partial[(size_t)blk * Hq + e + j] =
        sacc[0][e + j] + sacc[1][e + j] + sacc[2][e + j] + sacc[3][e + j];
}

// ---------------------------------------------------------------- fused: reduce partials/masksum + pooled @ W2 split-K
__global__ __launch_bounds__(256) void k_gemm2p(const float* __restrict__ partial,
                                                const float* __restrict__ mask,
                                                const float* __restrict__ w2,
                                                const int* __restrict__ lid,
                                                float* __restrict__ g2part) {
  __shared__ float pl[256];
  __shared__ float wsum[4];
  int blk = blockIdx.x;
  int b = blk >> 3; int ch = (blk >> 2) & 1; int ks = blk & 3;
  int tid = threadIdx.x;
  int lang = lid[b];
  // masksum (redundant per block — trivial)
  float mv = mask[b * Sq + tid] + mask[b * Sq + 256 + tid];
#pragma unroll
  for (int off = 1; off < 64; off <<= 1) mv += __shfl_xor(mv, off, 64);
  if ((tid & 63) == 0) wsum[tid >> 6] = mv;
  __syncthreads();
  float inv = 1.0f / (wsum[0] + wsum[1] + wsum[2] + wsum[3]);
  // pooled slice [ks*256 + tid] = sum of 8 chunk-partials * inv
  float s = 0.f;
#pragma unroll
  for (int c = 0; c < 8; c++) s += partial[((size_t)(b * 8 + c)) * Hq + ks * 256 + tid];
  pl[tid] = s * inv;
  __syncthreads();
  int col = ch * 512 + tid * 2;
  const float* W = w2 + (size_t)lang * Hq * Hq + (size_t)ks * 256 * Hq + col;
  float a0 = 0.f, a1 = 0.f;
  for (int e0 = 0; e0 < 256; e0 += 8) {
    float2 w[8];
#pragma unroll
    for (int j = 0; j < 8; j++) w[j] = *(const float2*)(W + (size_t)(e0 + j) * Hq);
#pragma unroll
    for (int j = 0; j < 8; j++) { float c = pl[e0 + j]; a0 += c * w[j].x; a1 += c * w[j].y; }
  }
  float2* dst = (float2*)(g2part + ((size_t)(b * 4 + ks) * Hq) + col);
  *dst = make_float2(a0, a1);
}

// ---------------------------------------------------------------- fused: sum k-slices + b2 + final matmul split-K
__global__ __launch_bounds__(256) void k_fpart(const float* __restrict__ g2part,
                                               const float* __restrict__ b2,
                                               const int* __restrict__ lid,
                                               const float* __restrict__ lda,
                                               const float* __restrict__ wf,
                                               float* __restrict__ fpart) {
  __shared__ float sc[128];
  int blk = blockIdx.x;
  int b = blk / 9, ks = blk % 9;
  int tid = threadIdx.x;
  int klen = (ks < 8) ? 128 : 100;
  int kbase = (ks < 8) ? ks * 128 : Hq;   // row offset into wf
  if (ks < 8) {
    if (tid < 128) {
      int col = kbase + tid;
      float v = b2[lid[b] * Hq + col];
#pragma unroll
      for (int c = 0; c < 4; c++) v += g2part[((size_t)(b * 4 + c)) * Hq + col];
      sc[tid] = v;
    }
  } else if (tid < 100) {
    sc[tid] = lda[b * Tq + tid];
  }
  __syncthreads();
  const float* W = wf + (size_t)kbase * Fq + tid * 2;
  float a0 = 0.f, a1 = 0.f;
  int k0 = 0;
  for (; k0 + 8 <= klen; k0 += 8) {
    float2 w[8];
#pragma unroll
    for (int j = 0; j < 8; j++) w[j] = *(const float2*)(W + (size_t)(k0 + j) * Fq);
#pragma unroll
    for (int j = 0; j < 8; j++) { float c = sc[k0 + j]; a0 += c * w[j].x; a1 += c * w[j].y; }
  }
  for (; k0 < klen; k0++) {
    float2 w = *(const float2*)(W + (size_t)k0 * Fq);
    float c = sc[k0];
    a0 += c * w.x; a1 += c * w.y;
  }
  float2* dst = (float2*)(fpart + (size_t)blk * Fq + tid * 2);
  *dst = make_float2(a0, a1);
}

// ---------------------------------------------------------------- reduce 9 slices + bf, LN, relu -> f32 out
__global__ __launch_bounds__(512) void k_final2(const float* __restrict__ fpart,
                                                const float* __restrict__ bff,
                                                const float* __restrict__ gf,
                                                const float* __restrict__ betaf,
                                                float* __restrict__ out) {
  __shared__ float rsum[8], rsq[8];
  int b = blockIdx.x; int tid = threadIdx.x;  // 512
  float acc = bff[tid];
#pragma unroll
  for (int ks = 0; ks < 9; ks++) acc += fpart[((size_t)b * 9 + ks) * Fq + tid];
  float s = acc, q = acc * acc;
#pragma unroll
  for (int off = 1; off < 64; off <<= 1) {
    s += __shfl_xor(s, off, 64);
    q += __shfl_xor(q, off, 64);
  }
  int w = tid >> 6, lane = tid & 63;
  if (lane == 0) { rsum[w] = s; rsq[w] = q; }
  __syncthreads();
  float S = 0.f, Q = 0.f;
#pragma unroll
  for (int i = 0; i < 8; i++) { S += rsum[i]; Q += rsq[i]; }
  float mu = S * (1.f / Fq);
  float var = Q * (1.f / Fq) - mu * mu;
  float y = (acc - mu) * rsqrtf(var + EPSq) * gf[tid] + betaf[tid];
  y = fmaxf(y, 0.f);
  out[b * Fq + tid] = y;   // f32 output
}

// ----------------------------------------------------------------
extern "C" void kernel_launch(void* const* d_in, const int* in_sizes, int n_in,
                              void* d_out, int out_size, void* d_ws, size_t ws_size,
                              hipStream_t stream) {
  const float* seq = (const float*)d_in[0];
  const float* mask = (const float*)d_in[1];
  const int* lid = (const int*)d_in[2];
  const float* lda = (const float*)d_in[3];
  const float* W1 = (const float*)d_in[4];
  const float* b1 = (const float*)d_in[5];
  const float* g1 = (const float*)d_in[6];
  const float* be1 = (const float*)d_in[7];
  const float* W2 = (const float*)d_in[8];
  const float* b2 = (const float*)d_in[9];
  const float* Wf = (const float*)d_in[10];
  const float* bff = (const float*)d_in[11];
  const float* gf = (const float*)d_in[12];
  const float* betaf = (const float*)d_in[13];
  float* out = (float*)d_out;

  // workspace layout (~46 MB)
  char* ws = (char*)d_ws;
  unsigned short* w1t = (unsigned short*)(ws);                    // 10,485,760 B
  unsigned short* h1bf = (unsigned short*)(ws + 10485760);        // 33,554,432 B
  float* partial = (float*)(ws + 44040192);                       //  1,048,576 B
  float* g2part = (float*)(ws + 45088768);                        //    524,288 B
  float* fpart = (float*)(ws + 45613056);                         //    589,824 B

  k_prep<<<5120, 256, 0, stream>>>(W1, w1t);
  k_gemm1<<<256, 512, 0, stream>>>(seq, w1t, b1, lid, h1bf);
  k_ln_pool<<<256, 256, 0, stream>>>(h1bf, g1, be1, mask, lid, partial);
  k_gemm2p<<<256, 256, 0, stream>>>(partial, mask, W2, lid, g2part);
  k_fpart<<<288, 256, 0, stream>>>(g2part, b2, lid, lda, Wf, fpart);
  k_final2<<<32, 512, 0, stream>>>(fpart, bff, gf, betaf, out);
}